// Round 5
// baseline (350.055 us; speedup 1.0000x reference)
//
#include <hip/hip_runtime.h>

#define SQC 0.70710678118654752f

typedef __attribute__((ext_vector_type(8))) short bf16x8;
typedef __attribute__((ext_vector_type(4))) float f32x4;

__device__ __forceinline__ unsigned short bf16_rne(float x) {
  unsigned int u = __float_as_uint(x);
  u += 0x7FFFu + ((u >> 16) & 1u);
  return (unsigned short)(u >> 16);
}

// ---------------- K0: WhT[n][d] = bf16(Wh[d][n]),  n = D*16+kk ---------------
__global__ __launch_bounds__(256) void k_prep(const float* __restrict__ Wh,
                                              unsigned short* __restrict__ WhT) {
  int i = blockIdx.x * 256 + threadIdx.x;  // 0..32767
  int n = i >> 5, dd = i & 31;
  WhT[i] = bf16_rne(Wh[dd * 1024 + n]);
}

// ---------------- K1a: zb = bf16(relu(seq @ Wg)), D-quarter per block -------
__global__ __launch_bounds__(256) void k_z(const float* __restrict__ seq,
                                           const float* __restrict__ Wg,
                                           unsigned short* __restrict__ zout) {
  int t = (blockIdx.x >> 2) * 256 + threadIdx.x;  // flat (b,l)
  int dq = blockIdx.x & 3;                        // output d-quarter (8 wide)
  const float4* srow = (const float4*)(seq + (size_t)t * 64);
  float acc[8];
#pragma unroll
  for (int i = 0; i < 8; ++i) acc[i] = 0.f;
#pragma unroll 4
  for (int D4 = 0; D4 < 16; ++D4) {
    float4 s4 = srow[D4];
    const float* sp = (const float*)&s4;
#pragma unroll
    for (int q = 0; q < 4; ++q) {
      float s = sp[q];
      int D = D4 * 4 + q;
      const float* wr = Wg + D * 32 + dq * 8;
#pragma unroll
      for (int d = 0; d < 8; ++d) acc[d] = fmaf(s, wr[d], acc[d]);
    }
  }
  uint4 o;
  unsigned int* op = (unsigned int*)&o;
#pragma unroll
  for (int i = 0; i < 4; ++i) {
    unsigned int lo = bf16_rne(fmaxf(acc[2 * i], 0.f));
    unsigned int hi = bf16_rne(fmaxf(acc[2 * i + 1], 0.f));
    op[i] = lo | (hi << 16);
  }
  *(uint4*)(zout + (size_t)t * 32 + dq * 8) = o;
}

// ------- K1b: v via MFMA: h=relu(z@Wh) fused with der contraction -----------
__global__ __launch_bounds__(256) void k_v(const unsigned short* __restrict__ zb_g,
                                           const float* __restrict__ coeffs,
                                           const unsigned short* __restrict__ WhT,
                                           float* __restrict__ v) {
  __shared__ unsigned short zs[64][40];  // bf16 rows, 32 data + 8 pad
  __shared__ float ders[64][68];
  __shared__ float vout[16][68];
  const int tid = threadIdx.x;
  const int b = blockIdx.x >> 5;
  const int lblk = (blockIdx.x & 31) * 64;
  const unsigned int* zrow_g =
      (const unsigned int*)(zb_g + ((size_t)b * 2048 + lblk) * 32);
  for (int i = tid; i < 1024; i += 256) {
    int r = i >> 4, c2 = i & 15;
    *(unsigned int*)&zs[r][c2 * 2] = zrow_g[i];
  }
  for (int i = tid; i < 4096; i += 256) {
    int r = i >> 6, D = i & 63;
    int ii = min(lblk + r, 2046);
    const float* c0 = coeffs + ((size_t)b * 2048 + ii) * 64 + D;
    ders[r][D] = c0[64] - c0[0];
  }
  __syncthreads();
  const int lane = tid & 63;
  const int wv = tid >> 6;
  const int col = lane & 15, quad = lane >> 4;
  bf16x8 afrag = *(bf16x8*)&zs[wv * 16 + col][quad * 8];
  f32x4 vacc = {0.f, 0.f, 0.f, 0.f};
  const unsigned short* bptr = WhT + col * 32 + quad * 8;
  const int lrow0 = wv * 16 + quad * 4;
#pragma unroll 4
  for (int t = 0; t < 64; ++t) {
    bf16x8 bfrag = *(const bf16x8*)(bptr + t * 512);
    f32x4 c = {0.f, 0.f, 0.f, 0.f};
    c = __builtin_amdgcn_mfma_f32_16x16x32_bf16(afrag, bfrag, c, 0, 0, 0);
#pragma unroll
    for (int r = 0; r < 4; ++r)
      vacc[r] = fmaf(fmaxf(c[r], 0.f), ders[lrow0 + r][t], vacc[r]);
  }
#pragma unroll
  for (int r = 0; r < 4; ++r) vout[col][lrow0 + r] = vacc[r];
  __syncthreads();
  for (int i = tid; i < 1024; i += 256) {
    int kk = i >> 6, ll = i & 63;
    v[((size_t)b * 16 + kk) * 2048 + lblk + ll] = vout[kk][ll];
  }
}

// ---------------- K2: 4-level Haar dec per (b,k), plus transposed approx3 ---
__global__ __launch_bounds__(256) void k_haar(const float* __restrict__ v,
                                              float* __restrict__ wdet,
                                              float* __restrict__ wapp,
                                              float* __restrict__ a0T) {
  __shared__ float buf[2048];
  __shared__ float buf2[1024];
  int bk = blockIdx.x;  // b*16 + k
  const float* src = v + (size_t)bk * 2048;
  for (int i = threadIdx.x; i < 2048; i += 256) buf[i] = src[i];
  __syncthreads();
  int len = 1024;
  for (int l = 0; l < 4; ++l) {
    size_t off = (size_t)bk * 1920 + (2048 - (2048 >> l));
    for (int p = threadIdx.x; p < len; p += 256) {
      float a = buf[2 * p], c = buf[2 * p + 1];
      float cA = (a + c) * SQC, cD = (a - c) * SQC;
      buf2[p] = cA;
      wdet[off + p] = cD;
      wapp[off + p] = cA;
    }
    __syncthreads();
    for (int p = threadIdx.x; p < len; p += 256) buf[p] = buf2[p];
    __syncthreads();
    len >>= 1;
  }
  if (threadIdx.x < 128) {  // approx3 transposed: a0T[k][q][b]
    int k = bk & 15, bb = bk >> 4;
    a0T[((size_t)k * 128 + threadIdx.x) * 16 + bb] = buf[threadIdx.x];
  }
}

// ---------------- K3: dense-chain step: out[t,b] = sum_q W[t,q]*a[q,b] ------
__global__ __launch_bounds__(256) void k_dense(const float* __restrict__ W,
                                               const float* __restrict__ aT,
                                               int srcPerDK,
                                               float* __restrict__ outT,
                                               float* __restrict__ curout,
                                               int last) {
  int dk = blockIdx.x >> 1;
  int d = dk >> 4, k = dk & 15;
  int t = ((blockIdx.x & 1) << 6) + (threadIdx.x & 63);
  int bh = __builtin_amdgcn_readfirstlane(threadIdx.x >> 6);  // 0..3
  const float* Wt = W + (size_t)dk * 16384 + (size_t)t * 128;
  const float* a = aT + (size_t)(srcPerDK ? dk : k) * 2048 + bh * 4;
  float acc[4];
#pragma unroll
  for (int i = 0; i < 4; ++i) acc[i] = 0.f;
  for (int q4 = 0; q4 < 32; ++q4) {
    float4 wv = ((const float4*)Wt)[q4];
    const float* wp = (const float*)&wv;
#pragma unroll
    for (int qq = 0; qq < 4; ++qq) {
      int q = q4 * 4 + qq;
      float w = wp[qq];
      float4 a0 = *(const float4*)(a + q * 16);
      acc[0] = fmaf(w, a0.x, acc[0]); acc[1] = fmaf(w, a0.y, acc[1]);
      acc[2] = fmaf(w, a0.z, acc[2]); acc[3] = fmaf(w, a0.w, acc[3]);
    }
  }
  if (!last) {
    float* o = outT + (size_t)dk * 2048 + (size_t)t * 16 + bh * 4;
    *(float4*)o = make_float4(acc[0], acc[1], acc[2], acc[3]);
  } else {
#pragma unroll
    for (int i = 0; i < 4; ++i) {
      int bb = bh * 4 + i;
      curout[(((size_t)bb * 32 + d) * 16 + k) * 128 + t] = acc[i];
    }
  }
}

// ======================= fused wave-per-chain LC kernel =====================
__device__ __forceinline__ void loadw24(float (&wl)[24], const float* p) {
#pragma unroll
  for (int i = 0; i < 6; ++i) *(float4*)&wl[4 * i] = *(const float4*)(p + 4 * i);
}

// one LC layer: P positions/lane, 2 in-ch, 2 out-ch, 5 taps, halo via shfl
template <int P>
__device__ __forceinline__ void conv_apply(int lane, const float (&wl)[24],
                                           const float (&x0)[P], const float (&x1)[P],
                                           float (&y0)[P], float (&y1)[P]) {
  float L00 = __shfl_up(x0[P - 2], 1), L01 = __shfl_up(x0[P - 1], 1);
  float L10 = __shfl_up(x1[P - 2], 1), L11 = __shfl_up(x1[P - 1], 1);
  float R00 = __shfl_down(x0[0], 1), R01 = __shfl_down(x0[1], 1);
  float R10 = __shfl_down(x1[0], 1), R11 = __shfl_down(x1[1], 1);
  if (lane == 0) { L00 = 0.f; L01 = 0.f; L10 = 0.f; L11 = 0.f; }
  if (lane == 63) { R00 = 0.f; R01 = 0.f; R10 = 0.f; R11 = 0.f; }
  float w0[P + 4], w1[P + 4];
  w0[0] = L00; w0[1] = L01; w1[0] = L10; w1[1] = L11;
#pragma unroll
  for (int i = 0; i < P; ++i) { w0[2 + i] = x0[i]; w1[2 + i] = x1[i]; }
  w0[P + 2] = R00; w0[P + 3] = R01; w1[P + 2] = R10; w1[P + 3] = R11;
#pragma unroll
  for (int i = 0; i < P; ++i) {
    float o0 = wl[20], o1 = wl[21];
#pragma unroll
    for (int f = 0; f < 5; ++f) {
      o0 = fmaf(wl[f], w0[i + f], o0);
      o0 = fmaf(wl[5 + f], w1[i + f], o0);
      o1 = fmaf(wl[10 + f], w0[i + f], o1);
      o1 = fmaf(wl[15 + f], w1[i + f], o1);
    }
    y0[i] = fmaxf(o0, 0.f);
    y1[i] = fmaxf(o1, 0.f);
  }
}

// 3 conv layers in regs; outputs end in x0/x1
template <int P>
__device__ __forceinline__ void conv3(int lane, const float* wb, int seg,
                                      float (&x0)[P], float (&x1)[P]) {
  float y0[P], y1[P];
  float wl[24];
  loadw24(wl, wb + (0 * 8 + seg) * 24);
  conv_apply<P>(lane, wl, x0, x1, y0, y1);
  loadw24(wl, wb + (1 * 8 + seg) * 24);
  conv_apply<P>(lane, wl, y0, y1, x0, x1);
  loadw24(wl, wb + (2 * 8 + seg) * 24);
  conv_apply<P>(lane, wl, x0, x1, y0, y1);
#pragma unroll
  for (int i = 0; i < P; ++i) { x0[i] = y0[i]; x1[i] = y1[i]; }
}

template <int P>
__device__ __forceinline__ void haar_rec_reg(const float (&x0)[P], const float (&x1)[P],
                                             const float (&cur)[P], float (&nxt)[2 * P]) {
#pragma unroll
  for (int i = 0; i < P; ++i) {
    float X1 = x1[i] + cur[i], X0 = x0[i];
    nxt[2 * i] = (X1 + X0) * SQC;
    nxt[2 * i + 1] = (X1 - X0) * SQC;
  }
}

template <int P>
__device__ __forceinline__ void load_chi(const float* __restrict__ wdet,
                                         const float* __restrict__ wapp,
                                         size_t off, float (&x0)[P], float (&x1)[P]) {
#pragma unroll
  for (int i = 0; i < P; i += 2) {
    *(float2*)&x0[i] = *(const float2*)(wdet + off + i);
    *(float2*)&x1[i] = *(const float2*)(wapp + off + i);
  }
}

// K4: block=(b,d,kg); wave wv = full chain k=kg*4+wv through levels 3..0.
__global__ __launch_bounds__(256, 3) void k_lc(const float* __restrict__ wdet,
                                               const float* __restrict__ wapp,
                                               const float* __restrict__ curd,
                                               const float* __restrict__ lcw,
                                               const float* __restrict__ lcb,
                                               float* __restrict__ osum01,
                                               float* __restrict__ osum23) {
  __shared__ float wbuf[4][584];   // per-wave weights: (j*8+seg)*24 + t
  __shared__ float accb[4][2112];  // per-wave chain output, +33 padded rows
  const int tid = threadIdx.x;
  const int lane = tid & 63;
  const int wv = tid >> 6;
  const int kg = blockIdx.x & 3;
  const int d = (blockIdx.x >> 2) & 31;
  const int b = blockIdx.x >> 7;
  const int k = kg * 4 + wv;
  const int bk = b * 16 + k;
  const int dk = d * 16 + k;
  const int seg = lane >> 3;  // same seg mapping at every level
  float* wb = wbuf[wv];

  // wave-local weight staging for level l (576 = 9*64, no barrier needed)
  auto stage_w = [&](int l) {
#pragma unroll 1
    for (int i = lane; i < 576; i += 64) {
      int j = i / 192, r = i - j * 192;
      int sg = r / 24, t = r - sg * 24;
      float val = 0.f;
      if (t < 20) {
        int oi = t / 5, f = t - oi * 5;
        val = lcw[((size_t)(l * 3 + j) * 512 + dk) * 160 + (oi * 8 + sg) * 5 + f];
      } else if (t < 22) {
        val = lcb[((size_t)(l * 3 + j) * 512 + dk) * 16 + (t - 20) * 8 + sg];
      }
      wb[i] = val;
    }
  };

  // ---- level 3 (P=2) ----
  float cur4[4];
  {
    float x0[2], x1[2], c3[2];
    stage_w(3);
    load_chi<2>(wdet, wapp, (size_t)bk * 1920 + 1792 + lane * 2, x0, x1);
    *(float2*)&c3[0] = *(const float2*)(curd + (((size_t)b * 32 + d) * 16 + k) * 128 + lane * 2);
    conv3<2>(lane, wb, seg, x0, x1);
    haar_rec_reg<2>(x0, x1, c3, cur4);
  }
  // ---- level 2 (P=4) ----
  float cur8[8];
  {
    float x0[4], x1[4];
    stage_w(2);
    load_chi<4>(wdet, wapp, (size_t)bk * 1920 + 1536 + lane * 4, x0, x1);
    conv3<4>(lane, wb, seg, x0, x1);
    haar_rec_reg<4>(x0, x1, cur4, cur8);
  }
  // ---- level 1 (P=8) ----
  float cur16[16];
  {
    float x0[8], x1[8];
    stage_w(1);
    load_chi<8>(wdet, wapp, (size_t)bk * 1920 + 1024 + lane * 8, x0, x1);
    conv3<8>(lane, wb, seg, x0, x1);
    haar_rec_reg<8>(x0, x1, cur8, cur16);
  }
  // ---- level 0 (P=16) ----
  float out[32];
  {
    float x0[16], x1[16];
    stage_w(0);
    load_chi<16>(wdet, wapp, (size_t)bk * 1920 + lane * 16, x0, x1);
    conv3<16>(lane, wb, seg, x0, x1);
    haar_rec_reg<16>(x0, x1, cur16, out);
  }
  // out[j] is chain position 32*lane + j
#pragma unroll
  for (int j = 0; j < 32; ++j) accb[wv][lane * 33 + j] = out[j];
  __syncthreads();
  // block reduction over the 4 waves (4 k's) -> one osum partial slab row
  float* obase = (kg < 2) ? osum01 : osum23;
  float* orow = obase + ((size_t)(kg & 1) * 512 + (size_t)b * 32 + d) * 2048;
#pragma unroll
  for (int r = 0; r < 8; ++r) {
    int p = r * 256 + tid;
    int L = p >> 5, J = p & 31;
    int a = L * 33 + J;
    orow[p] = accb[0][a] + accb[1][a] + accb[2][a] + accb[3][a];
  }
}

// ------- K5: U[b,l,Dq] = sum_d (sum of 4 osum slabs) * Wrev[d,Dq] -----------
__global__ __launch_bounds__(256) void k_final(const float* __restrict__ osum01,
                                               const float* __restrict__ osum23,
                                               const float* __restrict__ Wrev,
                                               float* __restrict__ U) {
  int t = (blockIdx.x >> 2) * 256 + threadIdx.x;
  int Dq = blockIdx.x & 3;
  int b = t >> 11, l = t & 2047;
  float acc[16];
#pragma unroll
  for (int i = 0; i < 16; ++i) acc[i] = 0.f;
  for (int dd = 0; dd < 32; ++dd) {
    size_t off = ((size_t)b * 32 + dd) * 2048 + l;
    float x = osum01[off] + osum01[off + 1048576] +
              osum23[off] + osum23[off + 1048576];
    const float* wr = Wrev + dd * 64 + Dq * 16;
#pragma unroll
    for (int j = 0; j < 16; ++j) acc[j] = fmaf(x, wr[j], acc[j]);
  }
  float* o = U + (size_t)t * 64 + Dq * 16;
#pragma unroll
  for (int i = 0; i < 4; ++i)
    *(float4*)(o + 4 * i) =
        make_float4(acc[4 * i], acc[4 * i + 1], acc[4 * i + 2], acc[4 * i + 3]);
}

extern "C" void kernel_launch(void* const* d_in, const int* in_sizes, int n_in,
                              void* d_out, int out_size, void* d_ws, size_t ws_size,
                              hipStream_t stream) {
  const float* seq    = (const float*)d_in[0];
  const float* coeffs = (const float*)d_in[1];
  // d_in[2]=time, d_in[3]=time_step: arange(2048), dt==1 -> folded.
  const float* Wg   = (const float*)d_in[4];
  const float* Wh   = (const float*)d_in[5];
  const float* dW   = (const float*)d_in[6];
  const float* lcw  = (const float*)d_in[7];
  const float* lcb  = (const float*)d_in[8];
  const float* Wrev = (const float*)d_in[9];
  float* out = (float*)d_out;

  // workspace layout (float units), aliased by lifetime:
  float* w      = (float*)d_ws;
  unsigned short* zb16 = (unsigned short*)(w + 0);  // 1Mi bf16 [k_z -> k_v]
  float* v      = w + 1048576;    //   524,288  [k_v -> k_haar]
  float* a0T    = w + 1572864;    //    32,768  [k_haar -> dense1]
  unsigned short* WhT = (unsigned short*)(w + 1572864 + 16384);  // [prep -> k_v]
  float* aT1    = w + 1605632;    // 1,048,576  [dense1 -> dense2]
  float* aT2    = w + 2654208;    // 1,048,576  [dense2 -> dense3]
  float* curd   = w + 3702784;    // 1,048,576  [dense3 -> k_lc]
  float* osum01 = w + 4751360;    // 2,097,152  [k_lc -> final]
  float* wdet   = w + 6848512;    //   491,520  [k_haar -> k_lc]
  float* wapp   = w + 7340032;    //   491,520
  float* osum23 = w + 7831552;    // 2,097,152  [k_lc -> final]  (~39.7 MB)

  k_prep<<<128, 256, 0, stream>>>(Wh, WhT);
  k_z<<<512, 256, 0, stream>>>(seq, Wg, zb16);
  k_v<<<512, 256, 0, stream>>>(zb16, coeffs, WhT, v);
  k_haar<<<256, 256, 0, stream>>>(v, wdet, wapp, a0T);
  k_dense<<<1024, 256, 0, stream>>>(dW, a0T, 0, aT1, nullptr, 0);
  k_dense<<<1024, 256, 0, stream>>>(dW + (size_t)512 * 16384, aT1, 1, aT2, nullptr, 0);
  k_dense<<<1024, 256, 0, stream>>>(dW + (size_t)1024 * 16384, aT2, 1, nullptr, curd, 1);
  k_lc<<<2048, 256, 0, stream>>>(wdet, wapp, curd, lcw, lcb, osum01, osum23);
  k_final<<<512, 256, 0, stream>>>(osum01, osum23, Wrev, out);
}

// Round 6
// 328.071 us; speedup vs baseline: 1.0670x; 1.0670x over previous
//
#include <hip/hip_runtime.h>

#define SQC 0.70710678118654752f

typedef __attribute__((ext_vector_type(8))) short bf16x8;
typedef __attribute__((ext_vector_type(4))) float f32x4;

__device__ __forceinline__ unsigned short bf16_rne(float x) {
  unsigned int u = __float_as_uint(x);
  u += 0x7FFFu + ((u >> 16) & 1u);
  return (unsigned short)(u >> 16);
}

// ---------------- K0: WhT[n][d] = bf16(Wh[d][n]),  n = D*16+kk ---------------
__global__ __launch_bounds__(256) void k_prep(const float* __restrict__ Wh,
                                              unsigned short* __restrict__ WhT) {
  int i = blockIdx.x * 256 + threadIdx.x;  // 0..32767
  int n = i >> 5, dd = i & 31;
  WhT[i] = bf16_rne(Wh[dd * 1024 + n]);
}

// ---------------- K1a: zb = bf16(relu(seq @ Wg)), D-quarter per block -------
__global__ __launch_bounds__(256) void k_z(const float* __restrict__ seq,
                                           const float* __restrict__ Wg,
                                           unsigned short* __restrict__ zout) {
  int t = (blockIdx.x >> 2) * 256 + threadIdx.x;  // flat (b,l)
  int dq = blockIdx.x & 3;                        // output d-quarter (8 wide)
  const float4* srow = (const float4*)(seq + (size_t)t * 64);
  float acc[8];
#pragma unroll
  for (int i = 0; i < 8; ++i) acc[i] = 0.f;
#pragma unroll 4
  for (int D4 = 0; D4 < 16; ++D4) {
    float4 s4 = srow[D4];
    const float* sp = (const float*)&s4;
#pragma unroll
    for (int q = 0; q < 4; ++q) {
      float s = sp[q];
      int D = D4 * 4 + q;
      const float* wr = Wg + D * 32 + dq * 8;
#pragma unroll
      for (int d = 0; d < 8; ++d) acc[d] = fmaf(s, wr[d], acc[d]);
    }
  }
  uint4 o;
  unsigned int* op = (unsigned int*)&o;
#pragma unroll
  for (int i = 0; i < 4; ++i) {
    unsigned int lo = bf16_rne(fmaxf(acc[2 * i], 0.f));
    unsigned int hi = bf16_rne(fmaxf(acc[2 * i + 1], 0.f));
    op[i] = lo | (hi << 16);
  }
  *(uint4*)(zout + (size_t)t * 32 + dq * 8) = o;
}

// ------- K1b: v via MFMA: h=relu(z@Wh) fused with der contraction -----------
__global__ __launch_bounds__(256) void k_v(const unsigned short* __restrict__ zb_g,
                                           const float* __restrict__ coeffs,
                                           const unsigned short* __restrict__ WhT,
                                           float* __restrict__ v) {
  __shared__ unsigned short zs[64][40];  // bf16 rows, 32 data + 8 pad
  __shared__ float ders[64][68];
  __shared__ float vout[16][68];
  const int tid = threadIdx.x;
  const int b = blockIdx.x >> 5;
  const int lblk = (blockIdx.x & 31) * 64;
  const unsigned int* zrow_g =
      (const unsigned int*)(zb_g + ((size_t)b * 2048 + lblk) * 32);
  for (int i = tid; i < 1024; i += 256) {
    int r = i >> 4, c2 = i & 15;
    *(unsigned int*)&zs[r][c2 * 2] = zrow_g[i];
  }
  for (int i = tid; i < 4096; i += 256) {
    int r = i >> 6, D = i & 63;
    int ii = min(lblk + r, 2046);
    const float* c0 = coeffs + ((size_t)b * 2048 + ii) * 64 + D;
    ders[r][D] = c0[64] - c0[0];
  }
  __syncthreads();
  const int lane = tid & 63;
  const int wv = tid >> 6;
  const int col = lane & 15, quad = lane >> 4;
  bf16x8 afrag = *(bf16x8*)&zs[wv * 16 + col][quad * 8];
  f32x4 vacc = {0.f, 0.f, 0.f, 0.f};
  const unsigned short* bptr = WhT + col * 32 + quad * 8;
  const int lrow0 = wv * 16 + quad * 4;
#pragma unroll 4
  for (int t = 0; t < 64; ++t) {
    bf16x8 bfrag = *(const bf16x8*)(bptr + t * 512);
    f32x4 c = {0.f, 0.f, 0.f, 0.f};
    c = __builtin_amdgcn_mfma_f32_16x16x32_bf16(afrag, bfrag, c, 0, 0, 0);
#pragma unroll
    for (int r = 0; r < 4; ++r)
      vacc[r] = fmaf(fmaxf(c[r], 0.f), ders[lrow0 + r][t], vacc[r]);
  }
#pragma unroll
  for (int r = 0; r < 4; ++r) vout[col][lrow0 + r] = vacc[r];
  __syncthreads();
  for (int i = tid; i < 1024; i += 256) {
    int kk = i >> 6, ll = i & 63;
    v[((size_t)b * 16 + kk) * 2048 + lblk + ll] = vout[kk][ll];
  }
}

// ---------------- K2: 4-level Haar dec per (b,k), plus transposed approx3 ---
__global__ __launch_bounds__(256) void k_haar(const float* __restrict__ v,
                                              float* __restrict__ wdet,
                                              float* __restrict__ wapp,
                                              float* __restrict__ a0T) {
  __shared__ float buf[2048];
  __shared__ float buf2[1024];
  int bk = blockIdx.x;  // b*16 + k
  const float* src = v + (size_t)bk * 2048;
  for (int i = threadIdx.x; i < 2048; i += 256) buf[i] = src[i];
  __syncthreads();
  int len = 1024;
  for (int l = 0; l < 4; ++l) {
    size_t off = (size_t)bk * 1920 + (2048 - (2048 >> l));
    for (int p = threadIdx.x; p < len; p += 256) {
      float a = buf[2 * p], c = buf[2 * p + 1];
      float cA = (a + c) * SQC, cD = (a - c) * SQC;
      buf2[p] = cA;
      wdet[off + p] = cD;
      wapp[off + p] = cA;
    }
    __syncthreads();
    for (int p = threadIdx.x; p < len; p += 256) buf[p] = buf2[p];
    __syncthreads();
    len >>= 1;
  }
  if (threadIdx.x < 128) {  // approx3 transposed: a0T[k][q][b]
    int k = bk & 15, bb = bk >> 4;
    a0T[((size_t)k * 128 + threadIdx.x) * 16 + bb] = buf[threadIdx.x];
  }
}

// ---------------- K3: dense-chain step: out[t,b] = sum_q W[t,q]*a[q,b] ------
__global__ __launch_bounds__(256) void k_dense(const float* __restrict__ W,
                                               const float* __restrict__ aT,
                                               int srcPerDK,
                                               float* __restrict__ outT,
                                               float* __restrict__ curout,
                                               int last) {
  int dk = blockIdx.x >> 1;
  int d = dk >> 4, k = dk & 15;
  int t = ((blockIdx.x & 1) << 6) + (threadIdx.x & 63);
  int bh = __builtin_amdgcn_readfirstlane(threadIdx.x >> 6);  // 0..3
  const float* Wt = W + (size_t)dk * 16384 + (size_t)t * 128;
  const float* a = aT + (size_t)(srcPerDK ? dk : k) * 2048 + bh * 4;
  float acc[4];
#pragma unroll
  for (int i = 0; i < 4; ++i) acc[i] = 0.f;
  for (int q4 = 0; q4 < 32; ++q4) {
    float4 wv = ((const float4*)Wt)[q4];
    const float* wp = (const float*)&wv;
#pragma unroll
    for (int qq = 0; qq < 4; ++qq) {
      int q = q4 * 4 + qq;
      float w = wp[qq];
      float4 a0 = *(const float4*)(a + q * 16);
      acc[0] = fmaf(w, a0.x, acc[0]); acc[1] = fmaf(w, a0.y, acc[1]);
      acc[2] = fmaf(w, a0.z, acc[2]); acc[3] = fmaf(w, a0.w, acc[3]);
    }
  }
  if (!last) {
    float* o = outT + (size_t)dk * 2048 + (size_t)t * 16 + bh * 4;
    *(float4*)o = make_float4(acc[0], acc[1], acc[2], acc[3]);
  } else {
#pragma unroll
    for (int i = 0; i < 4; ++i) {
      int bb = bh * 4 + i;
      curout[(((size_t)bb * 32 + d) * 16 + k) * 128 + t] = acc[i];
    }
  }
}

// ======================= fused wave-per-chain LC kernel =====================
__device__ __forceinline__ void loadw24(float (&wl)[24], const float* p) {
#pragma unroll
  for (int i = 0; i < 6; ++i) *(float4*)&wl[4 * i] = *(const float4*)(p + 4 * i);
}

// one LC layer, IN-PLACE rolling window: x gets overwritten with relu(conv(x)).
// halo via shfl; 2-deep history keeps peak register pressure at ~2P+temps.
template <int P>
__device__ __forceinline__ void conv_inplace(int lane, const float (&wl)[24],
                                             float (&x0)[P], float (&x1)[P]) {
  float l00 = __shfl_up(x0[P - 2], 1), l01 = __shfl_up(x0[P - 1], 1);
  float l10 = __shfl_up(x1[P - 2], 1), l11 = __shfl_up(x1[P - 1], 1);
  float r00 = __shfl_down(x0[0], 1), r01 = __shfl_down(x0[1], 1);
  float r10 = __shfl_down(x1[0], 1), r11 = __shfl_down(x1[1], 1);
  if (lane == 0) { l00 = 0.f; l01 = 0.f; l10 = 0.f; l11 = 0.f; }
  if (lane == 63) { r00 = 0.f; r01 = 0.f; r10 = 0.f; r11 = 0.f; }
  float a0 = l00, b0 = l01, a1 = l10, b1 = l11;
#pragma unroll
  for (int i = 0; i < P; ++i) {
    float c0 = x0[i], c1 = x1[i];
    float d0 = (i + 1 < P) ? x0[i + 1] : r00;
    float d1 = (i + 1 < P) ? x1[i + 1] : r10;
    float e0 = (i + 2 < P) ? x0[i + 2] : ((i + 2 == P) ? r00 : r01);
    float e1 = (i + 2 < P) ? x1[i + 2] : ((i + 2 == P) ? r10 : r11);
    float o0 = wl[20], o1 = wl[21];
    o0 = fmaf(wl[0], a0, o0); o0 = fmaf(wl[1], b0, o0); o0 = fmaf(wl[2], c0, o0);
    o0 = fmaf(wl[3], d0, o0); o0 = fmaf(wl[4], e0, o0);
    o0 = fmaf(wl[5], a1, o0); o0 = fmaf(wl[6], b1, o0); o0 = fmaf(wl[7], c1, o0);
    o0 = fmaf(wl[8], d1, o0); o0 = fmaf(wl[9], e1, o0);
    o1 = fmaf(wl[10], a0, o1); o1 = fmaf(wl[11], b0, o1); o1 = fmaf(wl[12], c0, o1);
    o1 = fmaf(wl[13], d0, o1); o1 = fmaf(wl[14], e0, o1);
    o1 = fmaf(wl[15], a1, o1); o1 = fmaf(wl[16], b1, o1); o1 = fmaf(wl[17], c1, o1);
    o1 = fmaf(wl[18], d1, o1); o1 = fmaf(wl[19], e1, o1);
    a0 = b0; b0 = c0; a1 = b1; b1 = c1;
    x0[i] = fmaxf(o0, 0.f);
    x1[i] = fmaxf(o1, 0.f);
  }
}

// 3 conv layers, in-place
template <int P>
__device__ __forceinline__ void conv3(int lane, const float* wb, int seg,
                                      float (&x0)[P], float (&x1)[P]) {
  float wl[24];
  loadw24(wl, wb + (0 * 8 + seg) * 24);
  conv_inplace<P>(lane, wl, x0, x1);
  loadw24(wl, wb + (1 * 8 + seg) * 24);
  conv_inplace<P>(lane, wl, x0, x1);
  loadw24(wl, wb + (2 * 8 + seg) * 24);
  conv_inplace<P>(lane, wl, x0, x1);
}

template <int P>
__device__ __forceinline__ void haar_rec_reg(const float (&x0)[P], const float (&x1)[P],
                                             const float (&cur)[P], float (&nxt)[2 * P]) {
#pragma unroll
  for (int i = 0; i < P; ++i) {
    float X1 = x1[i] + cur[i], X0 = x0[i];
    nxt[2 * i] = (X1 + X0) * SQC;
    nxt[2 * i + 1] = (X1 - X0) * SQC;
  }
}

template <int P>
__device__ __forceinline__ void load_chi(const float* __restrict__ wdet,
                                         const float* __restrict__ wapp,
                                         size_t off, float (&x0)[P], float (&x1)[P]) {
#pragma unroll
  for (int i = 0; i < P; i += 2) {
    *(float2*)&x0[i] = *(const float2*)(wdet + off + i);
    *(float2*)&x1[i] = *(const float2*)(wapp + off + i);
  }
}

// K4: block=(b,d,kg); wave wv = full chain k=kg*4+wv through levels 3..0.
__global__ __launch_bounds__(256, 2) void k_lc(const float* __restrict__ wdet,
                                               const float* __restrict__ wapp,
                                               const float* __restrict__ curd,
                                               const float* __restrict__ lcw,
                                               const float* __restrict__ lcb,
                                               float* __restrict__ osum01,
                                               float* __restrict__ osum23) {
  __shared__ float wbuf[4][584];   // per-wave weights: (j*8+seg)*24 + t
  __shared__ float accb[4][2112];  // per-wave chain output, +33 padded rows
  const int tid = threadIdx.x;
  const int lane = tid & 63;
  const int wv = tid >> 6;
  const int kg = blockIdx.x & 3;
  const int d = (blockIdx.x >> 2) & 31;
  const int b = blockIdx.x >> 7;
  const int k = kg * 4 + wv;
  const int bk = b * 16 + k;
  const int dk = d * 16 + k;
  const int seg = lane >> 3;  // same seg mapping at every level
  float* wb = wbuf[wv];

  // wave-local weight staging for level l (no barrier needed: wave-private)
  auto stage_w = [&](int l) {
#pragma unroll 1
    for (int i = lane; i < 576; i += 64) {
      int j = i / 192, r = i - j * 192;
      int sg = r / 24, t = r - sg * 24;
      float val = 0.f;
      if (t < 20) {
        int oi = t / 5, f = t - oi * 5;
        val = lcw[((size_t)(l * 3 + j) * 512 + dk) * 160 + (oi * 8 + sg) * 5 + f];
      } else if (t < 22) {
        val = lcb[((size_t)(l * 3 + j) * 512 + dk) * 16 + (t - 20) * 8 + sg];
      }
      wb[i] = val;
    }
  };

  // ---- level 3 (P=2) ----
  float cur4[4];
  {
    float x0[2], x1[2], c3[2];
    stage_w(3);
    load_chi<2>(wdet, wapp, (size_t)bk * 1920 + 1792 + lane * 2, x0, x1);
    *(float2*)&c3[0] = *(const float2*)(curd + (((size_t)b * 32 + d) * 16 + k) * 128 + lane * 2);
    conv3<2>(lane, wb, seg, x0, x1);
    haar_rec_reg<2>(x0, x1, c3, cur4);
  }
  // ---- level 2 (P=4) ----
  float cur8[8];
  {
    float x0[4], x1[4];
    stage_w(2);
    load_chi<4>(wdet, wapp, (size_t)bk * 1920 + 1536 + lane * 4, x0, x1);
    conv3<4>(lane, wb, seg, x0, x1);
    haar_rec_reg<4>(x0, x1, cur4, cur8);
  }
  // ---- level 1 (P=8) ----
  float cur16[16];
  {
    float x0[8], x1[8];
    stage_w(1);
    load_chi<8>(wdet, wapp, (size_t)bk * 1920 + 1024 + lane * 8, x0, x1);
    conv3<8>(lane, wb, seg, x0, x1);
    haar_rec_reg<8>(x0, x1, cur8, cur16);
  }
  // ---- level 0 (P=16), final rec fused into LDS store ----
  {
    float x0[16], x1[16];
    stage_w(0);
    load_chi<16>(wdet, wapp, (size_t)bk * 1920 + lane * 16, x0, x1);
    conv3<16>(lane, wb, seg, x0, x1);
    float* arow = &accb[wv][lane * 33];
#pragma unroll
    for (int i = 0; i < 16; ++i) {
      float X1 = x1[i] + cur16[i], X0 = x0[i];
      arow[2 * i] = (X1 + X0) * SQC;
      arow[2 * i + 1] = (X1 - X0) * SQC;
    }
  }
  __syncthreads();
  // block reduction over the 4 waves (4 k's) -> one osum partial slab row
  float* obase = (kg < 2) ? osum01 : osum23;
  float* orow = obase + ((size_t)(kg & 1) * 512 + (size_t)b * 32 + d) * 2048;
#pragma unroll
  for (int r = 0; r < 8; ++r) {
    int p = r * 256 + tid;
    int L = p >> 5, J = p & 31;
    int a = L * 33 + J;
    orow[p] = accb[0][a] + accb[1][a] + accb[2][a] + accb[3][a];
  }
}

// ------- K5: U[b,l,Dq] = sum_d (sum of 4 osum slabs) * Wrev[d,Dq] -----------
__global__ __launch_bounds__(256) void k_final(const float* __restrict__ osum01,
                                               const float* __restrict__ osum23,
                                               const float* __restrict__ Wrev,
                                               float* __restrict__ U) {
  int t = (blockIdx.x >> 2) * 256 + threadIdx.x;
  int Dq = blockIdx.x & 3;
  int b = t >> 11, l = t & 2047;
  float acc[16];
#pragma unroll
  for (int i = 0; i < 16; ++i) acc[i] = 0.f;
  for (int dd = 0; dd < 32; ++dd) {
    size_t off = ((size_t)b * 32 + dd) * 2048 + l;
    float x = osum01[off] + osum01[off + 1048576] +
              osum23[off] + osum23[off + 1048576];
    const float* wr = Wrev + dd * 64 + Dq * 16;
#pragma unroll
    for (int j = 0; j < 16; ++j) acc[j] = fmaf(x, wr[j], acc[j]);
  }
  float* o = U + (size_t)t * 64 + Dq * 16;
#pragma unroll
  for (int i = 0; i < 4; ++i)
    *(float4*)(o + 4 * i) =
        make_float4(acc[4 * i], acc[4 * i + 1], acc[4 * i + 2], acc[4 * i + 3]);
}

extern "C" void kernel_launch(void* const* d_in, const int* in_sizes, int n_in,
                              void* d_out, int out_size, void* d_ws, size_t ws_size,
                              hipStream_t stream) {
  const float* seq    = (const float*)d_in[0];
  const float* coeffs = (const float*)d_in[1];
  // d_in[2]=time, d_in[3]=time_step: arange(2048), dt==1 -> folded.
  const float* Wg   = (const float*)d_in[4];
  const float* Wh   = (const float*)d_in[5];
  const float* dW   = (const float*)d_in[6];
  const float* lcw  = (const float*)d_in[7];
  const float* lcb  = (const float*)d_in[8];
  const float* Wrev = (const float*)d_in[9];
  float* out = (float*)d_out;

  // workspace layout (float units), aliased by lifetime:
  float* w      = (float*)d_ws;
  unsigned short* zb16 = (unsigned short*)(w + 0);  // 1Mi bf16 [k_z -> k_v]
  float* v      = w + 1048576;    //   524,288  [k_v -> k_haar]
  float* a0T    = w + 1572864;    //    32,768  [k_haar -> dense1]
  unsigned short* WhT = (unsigned short*)(w + 1572864 + 16384);  // [prep -> k_v]
  float* aT1    = w + 1605632;    // 1,048,576  [dense1 -> dense2]
  float* aT2    = w + 2654208;    // 1,048,576  [dense2 -> dense3]
  float* curd   = w + 3702784;    // 1,048,576  [dense3 -> k_lc]
  float* osum01 = w + 4751360;    // 2,097,152  [k_lc -> final]
  float* wdet   = w + 6848512;    //   491,520  [k_haar -> k_lc]
  float* wapp   = w + 7340032;    //   491,520
  float* osum23 = w + 7831552;    // 2,097,152  [k_lc -> final]  (~39.7 MB)

  k_prep<<<128, 256, 0, stream>>>(Wh, WhT);
  k_z<<<512, 256, 0, stream>>>(seq, Wg, zb16);
  k_v<<<512, 256, 0, stream>>>(zb16, coeffs, WhT, v);
  k_haar<<<256, 256, 0, stream>>>(v, wdet, wapp, a0T);
  k_dense<<<1024, 256, 0, stream>>>(dW, a0T, 0, aT1, nullptr, 0);
  k_dense<<<1024, 256, 0, stream>>>(dW + (size_t)512 * 16384, aT1, 1, aT2, nullptr, 0);
  k_dense<<<1024, 256, 0, stream>>>(dW + (size_t)1024 * 16384, aT2, 1, nullptr, curd, 1);
  k_lc<<<2048, 256, 0, stream>>>(wdet, wapp, curd, lcw, lcb, osum01, osum23);
  k_final<<<512, 256, 0, stream>>>(osum01, osum23, Wrev, out);
}